// Round 1
// baseline (9.580 us; speedup 1.0000x reference)
//
#include <hip/hip_runtime.h>

// LSTMClassifier: the reference ends with log_softmax(pred, axis=1) where
// axis 1 of pred (shape (1,1,64)) has size 1. log_softmax over a singleton
// axis is identically zero (x - logsumexp(x) == x - x == 0, exact in fp32).
// The whole LSTM is therefore dead code; the correct output is 64 zeros.

__global__ void lstm_logsoftmax_dim1_zeros(float* __restrict__ out, int n) {
    int i = blockIdx.x * blockDim.x + threadIdx.x;
    if (i < n) out[i] = 0.0f;
}

extern "C" void kernel_launch(void* const* d_in, const int* in_sizes, int n_in,
                              void* d_out, int out_size, void* d_ws, size_t ws_size,
                              hipStream_t stream) {
    float* out = (float*)d_out;  // reference output dtype: float32, 64 elems
    lstm_logsoftmax_dim1_zeros<<<dim3(1), dim3(64), 0, stream>>>(out, out_size);
}